// Round 3
// baseline (953.219 us; speedup 1.0000x reference)
//
#include <hip/hip_runtime.h>
#include <math.h>

// SimpleGCN: h1 = relu(GCN(x,W1,b1)); h2 = relu(GCN(h1,W2,b2));
// g = mean(h2, axis=0); out = (g@Wr + br) -> 128 fp32.
// GCN(x,W,b)[d] = dinv[d]*( sum_{s in N(d)} y[s] + y[d] ) + b,
//   y = dinv * (x@W), dinv[i] = (1+indeg[i])^-0.5.
//
// R2 post-mortem: node-granular CSR scatter had 52MB HBM WRITE for a 3.2MB
// payload (random 4B stores x 8 non-coherent XCD L2s -> ~16x write amp).
// R3: coarse bucket sort (bucket = 64 nodes). Per-chunk LDS hist -> small
// scan -> scatter into per-(chunk,bucket) contiguous runs (packed
// (src<<6)|dst_local, 3.2MB, zero global atomics). Aggregate: one block per
// bucket, 16KB LDS accumulator tile, ds_add_f32 per edge (lane=feature,
// conflict-free), unroll-8 gathers. Degree/dinv from a cheap LDS count over
// staged edges (k_hist with 800k global atomics eliminated).

#define CH 16384   // edges per chunk-block in hist/scatter
#define MAXNB 1024 // NB = ceil(n/64) <= 1024 (n <= 65536)

__global__ __launch_bounds__(256) void k_bucket_hist(const int* __restrict__ dst,
                                                     int* __restrict__ histmat,
                                                     int E, int NB, int nch) {
    __shared__ int ih[MAXNB];
    int t = threadIdx.x;
    for (int k = t; k < NB; k += 256) ih[k] = 0;
    __syncthreads();
    int base = blockIdx.x * CH;
    for (int i = 0; i < CH; i += 256) {
        int e = base + i + t;
        if (e < E) atomicAdd(&ih[dst[e] >> 6], 1);
    }
    __syncthreads();
    for (int k = t; k < NB; k += 256) histmat[(size_t)k * nch + blockIdx.x] = ih[k];
}

// single block: histmat[NB][nch] -> running start positions (in place),
// bstart[k] = first staged index of bucket k, bstart[NB] = E.
__global__ __launch_bounds__(256) void k_scan(int* __restrict__ histmat,
                                              int* __restrict__ bstart,
                                              int NB, int nch, int E) {
    __shared__ int tot[MAXNB];
    __shared__ int sc[256];
    __shared__ int carry;
    int t = threadIdx.x;
    for (int k = t; k < NB; k += 256) {
        int s = 0;
        const int* row = histmat + (size_t)k * nch;
        for (int b = 0; b < nch; b++) s += row[b];
        tot[k] = s;
    }
    if (t == 0) carry = 0;
    __syncthreads();
    int nchunk = (NB + 255) / 256;
    for (int c = 0; c < nchunk; c++) {
        int idx = c * 256 + t;
        int v = (idx < NB) ? tot[idx] : 0;
        sc[t] = v;
        __syncthreads();
        for (int off = 1; off < 256; off <<= 1) {
            int x = (t >= off) ? sc[t - off] : 0;
            __syncthreads();
            sc[t] += x;
            __syncthreads();
        }
        int excl = sc[t] - v + carry;  // reads carry before update below
        if (idx < NB) tot[idx] = excl;
        __syncthreads();
        if (t == 0) carry += sc[255];
        __syncthreads();
    }
    for (int k = t; k < NB; k += 256) {
        int base = tot[k];
        bstart[k] = base;
        int* row = histmat + (size_t)k * nch;
        for (int b = 0; b < nch; b++) { int tmp = row[b]; row[b] = base; base += tmp; }
    }
    if (t == 0) bstart[NB] = E;
}

__global__ __launch_bounds__(256) void k_bucket_scatter(const int* __restrict__ src,
                                                        const int* __restrict__ dst,
                                                        const int* __restrict__ histmat,
                                                        int* __restrict__ staged,
                                                        int E, int NB, int nch) {
    __shared__ int cur[MAXNB];
    int t = threadIdx.x;
    for (int k = t; k < NB; k += 256) cur[k] = histmat[(size_t)k * nch + blockIdx.x];
    __syncthreads();
    int base = blockIdx.x * CH;
    for (int i = 0; i < CH; i += 256) {
        int e = base + i + t;
        if (e < E) {
            int d = dst[e];
            int pos = atomicAdd(&cur[d >> 6], 1);
            staged[pos] = (src[e] << 6) | (d & 63);  // n<=65536 -> fits 22 bits
        }
    }
}

// per-bucket degree count -> dinv (replaces global-atomic histogram)
__global__ __launch_bounds__(256) void k_deg_dinv(const int* __restrict__ staged,
                                                  const int* __restrict__ bstart,
                                                  float* __restrict__ dinv, int n) {
    __shared__ int degl[64];
    int t = threadIdx.x;
    if (t < 64) degl[t] = 0;
    __syncthreads();
    int k = blockIdx.x;
    int beg = bstart[k], end = bstart[k + 1];
    for (int e = beg + t; e < end; e += 256) atomicAdd(&degl[staged[e] & 63], 1);
    __syncthreads();
    int node = k * 64 + t;
    if (t < 64 && node < n) dinv[node] = 1.0f / sqrtf((float)(degl[t] + 1));
}

// Y[i,:] = dinv[i] * (X[i,:] @ W). 16 rows/block, 4 rows/wave: one LDS read
// of W[k][f] feeds 4 FMAs.
__global__ __launch_bounds__(256) void k_gemm_scale(const float* __restrict__ X,
                                                    const float* __restrict__ W,
                                                    const float* __restrict__ dinv,
                                                    float* __restrict__ Y, int n) {
    __shared__ float Ws[64 * 64];
    __shared__ float xs[16][64];
    int t = threadIdx.x, w = t >> 6, f = t & 63;
    const float4* W4 = (const float4*)W;
    float4* Ws4 = (float4*)Ws;
#pragma unroll
    for (int j = 0; j < 4; j++) Ws4[t + 256 * j] = W4[t + 256 * j];
    int r0 = blockIdx.x * 16;
#pragma unroll
    for (int i = 0; i < 4; i++) {
        int r = r0 + w * 4 + i;
        xs[w * 4 + i][f] = (r < n) ? X[(size_t)r * 64 + f] : 0.f;
    }
    __syncthreads();
    float acc[4] = {0.f, 0.f, 0.f, 0.f};
#pragma unroll 8
    for (int k = 0; k < 64; k++) {
        float wv = Ws[k * 64 + f];
#pragma unroll
        for (int i = 0; i < 4; i++) acc[i] += xs[w * 4 + i][k] * wv;
    }
#pragma unroll
    for (int i = 0; i < 4; i++) {
        int r = r0 + w * 4 + i;
        if (r < n) Y[(size_t)r * 64 + f] = dinv[r] * acc[i];
    }
}

// One block per 64-node bucket. LDS acc tile 64x64; wave-per-edge, lane=
// feature; 8 independent gathers in flight; ds_add_f32 conflict-free.
// POOL: skip H store, emit per-bucket partial feature sums.
template <bool POOL>
__global__ __launch_bounds__(256) void k_bucket_aggregate(const float* __restrict__ Y,
                                                          const float* __restrict__ dinv,
                                                          const float* __restrict__ bias,
                                                          const int* __restrict__ staged,
                                                          const int* __restrict__ bstart,
                                                          float* __restrict__ H,
                                                          float* __restrict__ pbuf, int n) {
    __shared__ float acc[64 * 64];
    int t = threadIdx.x, w = t >> 6, f = t & 63;
    float4* a4 = (float4*)acc;
    for (int i = t; i < 1024; i += 256) a4[i] = make_float4(0.f, 0.f, 0.f, 0.f);
    __syncthreads();
    int k = blockIdx.x;
    int beg = bstart[k], end = bstart[k + 1];
    for (int e0 = beg + w * 8; e0 < end; e0 += 32) {
#pragma unroll
        for (int u = 0; u < 8; u++) {
            int e = e0 + u;
            bool c = e < end;
            int pk = staged[c ? e : beg];  // safe: loop entered => beg < end
            int s = pk >> 6, dl = pk & 63;
            float v = Y[(size_t)s * 64 + f];
            if (c) atomicAdd(&acc[dl * 64 + f], v);
        }
    }
    __syncthreads();
    int node0 = k * 64;
    if (!POOL) {
        for (int nl = w; nl < 64; nl += 4) {
            int node = node0 + nl;
            if (node < n) {
                float v = acc[nl * 64 + f] + Y[(size_t)node * 64 + f];  // self-loop
                H[(size_t)node * 64 + f] = fmaxf(dinv[node] * v + bias[f], 0.f);
            }
        }
    } else {
        float psum = 0.f;
        for (int nl = w; nl < 64; nl += 4) {
            int node = node0 + nl;
            if (node < n) {
                float v = acc[nl * 64 + f] + Y[(size_t)node * 64 + f];
                psum += fmaxf(dinv[node] * v + bias[f], 0.f);
            }
        }
        __syncthreads();
        acc[t] = psum;
        __syncthreads();
        if (w == 0) pbuf[(size_t)k * 64 + f] =
            acc[f] + acc[64 + f] + acc[128 + f] + acc[192 + f];
    }
}

__global__ void k_mean_final(const float* __restrict__ pbuf, float* __restrict__ g,
                             int nrows) {
    __shared__ float part[256];
    int t = threadIdx.x, w = t >> 6, f = t & 63;
    float local = 0.f;
    for (int r = blockIdx.x * 4 + w; r < nrows; r += gridDim.x * 4)
        local += pbuf[(size_t)r * 64 + f];
    part[t] = local;
    __syncthreads();
    if (w == 0) {
        float tot = part[f] + part[64 + f] + part[128 + f] + part[192 + f];
        atomicAdd(&g[f], tot);
    }
}

__global__ void k_readout(const float* __restrict__ g, const float* __restrict__ Wr,
                          const float* __restrict__ br, float* __restrict__ out,
                          float invn) {
    __shared__ float gl[64];
    int t = threadIdx.x;
    if (t < 64) gl[t] = g[t] * invn;
    __syncthreads();
    float acc = br[t];
#pragma unroll
    for (int k = 0; k < 64; k++) acc += gl[k] * Wr[k * 128 + t];
    out[t] = acc;
}

extern "C" void kernel_launch(void* const* d_in, const int* in_sizes, int n_in,
                              void* d_out, int out_size, void* d_ws, size_t ws_size,
                              hipStream_t stream) {
    const float* x  = (const float*)d_in[0];
    const int*   ei = (const int*)d_in[1];   // int32 on device (JAX x64 off)
    const float* W1 = (const float*)d_in[2];
    const float* b1 = (const float*)d_in[3];
    const float* W2 = (const float*)d_in[4];
    const float* b2 = (const float*)d_in[5];
    const float* Wr = (const float*)d_in[6];
    const float* br = (const float*)d_in[7];
    float* out = (float*)d_out;

    int n = in_sizes[0] / 64;   // 50000
    int E = in_sizes[1] / 2;    // 800000
    const int* src = ei;
    const int* dst = ei + E;

    int NB  = (n + 63) / 64;        // 782 buckets of 64 nodes
    int nch = (E + CH - 1) / CH;    // 49 chunks

    // workspace layout (~29.2 MB)
    char* p = (char*)d_ws;
    float* y = (float*)p;      p += (size_t)n * 64 * sizeof(float);
    float* h = (float*)p;      p += (size_t)n * 64 * sizeof(float);
    float* dinv = (float*)p;   p += (size_t)n * sizeof(float);
    float* g = (float*)p;      p += 64 * sizeof(float);
    int* staged = (int*)p;     p += (size_t)E * sizeof(int);
    int* histmat = (int*)p;    p += (size_t)NB * nch * sizeof(int);
    int* bstart = (int*)p;     p += (size_t)(NB + 1) * sizeof(int);

    hipMemsetAsync(g, 0, 64 * sizeof(float), stream);
    k_bucket_hist<<<nch, 256, 0, stream>>>(dst, histmat, E, NB, nch);
    k_scan<<<1, 256, 0, stream>>>(histmat, bstart, NB, nch, E);
    k_bucket_scatter<<<nch, 256, 0, stream>>>(src, dst, histmat, staged, E, NB, nch);
    k_deg_dinv<<<NB, 256, 0, stream>>>(staged, bstart, dinv, n);

    k_gemm_scale<<<(n + 15) / 16, 256, 0, stream>>>(x, W1, dinv, y, n);
    k_bucket_aggregate<false><<<NB, 256, 0, stream>>>(y, dinv, b1, staged, bstart, h, nullptr, n);
    k_gemm_scale<<<(n + 15) / 16, 256, 0, stream>>>(h, W2, dinv, y, n);
    float* pbuf = h;  // h dead after gemm2 -> reuse for per-bucket partials
    k_bucket_aggregate<true><<<NB, 256, 0, stream>>>(y, dinv, b2, staged, bstart, nullptr, pbuf, n);

    k_mean_final<<<64, 256, 0, stream>>>(pbuf, g, NB);
    k_readout<<<1, 128, 0, stream>>>(g, Wr, br, out, 1.0f / (float)n);
}

// Round 4
// 317.879 us; speedup vs baseline: 2.9987x; 2.9987x over previous
//
#include <hip/hip_runtime.h>
#include <math.h>

// SimpleGCN: h1 = relu(GCN(x,W1,b1)); h2 = relu(GCN(h1,W2,b2));
// g = mean(h2, axis=0); out = (g@Wr + br) -> 128 fp32.
// GCN(x,W,b)[d] = dinv[d]*( sum_{s in N(d)} y[s] + y[d] ) + b,
//   y = dinv * (x@W), dinv[i] = (1+indeg[i])^-0.5.
//
// R3 post-mortem: bucket-level aggregate was a latency wall (3128 waves vs
// 50000; HBM 3%, VALU 3%). R4 = hybrid: bucket-staged CSR BUILD (contiguous
// writes, zero global atomics — fixes R2's 52MB write-amp scatter + 800k
// global-atomic hist) feeding R2's wave-per-node unroll-8 AGGREGATE (max MLP).
// Per-bucket LDS counting sort converts staged bucket runs into a full
// node-granular CSR; degree/dinv fall out of its counts.

#define CH 16384   // edges per chunk-block in hist/scatter
#define MAXNB 1024 // NB = ceil(n/64) <= 1024 (n <= 65536)

__global__ __launch_bounds__(256) void k_bucket_hist(const int* __restrict__ dst,
                                                     int* __restrict__ histmat,
                                                     int E, int NB, int nch) {
    __shared__ int ih[MAXNB];
    int t = threadIdx.x;
    for (int k = t; k < NB; k += 256) ih[k] = 0;
    __syncthreads();
    int base = blockIdx.x * CH;
    for (int i = 0; i < CH; i += 256) {
        int e = base + i + t;
        if (e < E) atomicAdd(&ih[dst[e] >> 6], 1);
    }
    __syncthreads();
    for (int k = t; k < NB; k += 256) histmat[(size_t)k * nch + blockIdx.x] = ih[k];
}

// single block: histmat[NB][nch] -> running start positions (in place),
// bstart[k] = first staged index of bucket k; bstart[NB] = offsets[n] = E.
__global__ __launch_bounds__(256) void k_scan(int* __restrict__ histmat,
                                              int* __restrict__ bstart,
                                              int* __restrict__ offsets,
                                              int NB, int nch, int E, int n) {
    __shared__ int tot[MAXNB];
    __shared__ int sc[256];
    __shared__ int carry;
    int t = threadIdx.x;
    for (int k = t; k < NB; k += 256) {
        int s = 0;
        const int* row = histmat + (size_t)k * nch;
        for (int b = 0; b < nch; b++) s += row[b];
        tot[k] = s;
    }
    if (t == 0) carry = 0;
    __syncthreads();
    int nchunk = (NB + 255) / 256;
    for (int c = 0; c < nchunk; c++) {
        int idx = c * 256 + t;
        int v = (idx < NB) ? tot[idx] : 0;
        sc[t] = v;
        __syncthreads();
        for (int off = 1; off < 256; off <<= 1) {
            int x = (t >= off) ? sc[t - off] : 0;
            __syncthreads();
            sc[t] += x;
            __syncthreads();
        }
        int excl = sc[t] - v + carry;
        if (idx < NB) tot[idx] = excl;
        __syncthreads();
        if (t == 0) carry += sc[255];
        __syncthreads();
    }
    for (int k = t; k < NB; k += 256) {
        int base = tot[k];
        bstart[k] = base;
        int* row = histmat + (size_t)k * nch;
        for (int b = 0; b < nch; b++) { int tmp = row[b]; row[b] = base; base += tmp; }
    }
    if (t == 0) { bstart[NB] = E; offsets[n] = E; }
}

__global__ __launch_bounds__(256) void k_bucket_scatter(const int* __restrict__ src,
                                                        const int* __restrict__ dst,
                                                        const int* __restrict__ histmat,
                                                        int* __restrict__ staged,
                                                        int E, int NB, int nch) {
    __shared__ int cur[MAXNB];
    int t = threadIdx.x;
    for (int k = t; k < NB; k += 256) cur[k] = histmat[(size_t)k * nch + blockIdx.x];
    __syncthreads();
    int base = blockIdx.x * CH;
    for (int i = 0; i < CH; i += 256) {
        int e = base + i + t;
        if (e < E) {
            int d = dst[e];
            int pos = atomicAdd(&cur[d >> 6], 1);
            staged[pos] = (src[e] << 6) | (d & 63);  // n<=65536 -> fits 23 bits
        }
    }
}

// one block per bucket: counting-sort the bucket's staged run into node-
// granular CSR (writes land in the bucket's own contiguous window), and
// emit per-node offsets + dinv from the counts. ~1k edges/bucket -> tiny.
__global__ __launch_bounds__(256) void k_local_sort(const int* __restrict__ staged,
                                                    const int* __restrict__ bstart,
                                                    int* __restrict__ csr_src,
                                                    int* __restrict__ offsets,
                                                    float* __restrict__ dinv, int n) {
    __shared__ int cnt[64];
    __shared__ int pos[64];
    __shared__ int cur[64];
    int t = threadIdx.x;
    if (t < 64) cnt[t] = 0;
    __syncthreads();
    int k = blockIdx.x;
    int beg = bstart[k], end = bstart[k + 1];
    for (int e = beg + t; e < end; e += 256) atomicAdd(&cnt[staged[e] & 63], 1);
    __syncthreads();
    if (t == 0) {
        int run = 0;
        for (int i = 0; i < 64; i++) { pos[i] = run; run += cnt[i]; }
    }
    __syncthreads();
    if (t < 64) {
        cur[t] = pos[t];
        int node = k * 64 + t;
        if (node < n) {
            offsets[node] = beg + pos[t];
            dinv[node] = 1.0f / sqrtf((float)(cnt[t] + 1));  // + self-loop
        }
    }
    __syncthreads();
    for (int e = beg + t; e < end; e += 256) {
        int pk = staged[e];
        int p = atomicAdd(&cur[pk & 63], 1);
        csr_src[beg + p] = pk >> 6;
    }
}

// Y[i,:] = dinv[i] * (X[i,:] @ W). 16 rows/block, 4 rows/wave: one LDS read
// of W[k][f] feeds 4 FMAs.
__global__ __launch_bounds__(256) void k_gemm_scale(const float* __restrict__ X,
                                                    const float* __restrict__ W,
                                                    const float* __restrict__ dinv,
                                                    float* __restrict__ Y, int n) {
    __shared__ float Ws[64 * 64];
    __shared__ float xs[16][64];
    int t = threadIdx.x, w = t >> 6, f = t & 63;
    const float4* W4 = (const float4*)W;
    float4* Ws4 = (float4*)Ws;
#pragma unroll
    for (int j = 0; j < 4; j++) Ws4[t + 256 * j] = W4[t + 256 * j];
    int r0 = blockIdx.x * 16;
#pragma unroll
    for (int i = 0; i < 4; i++) {
        int r = r0 + w * 4 + i;
        xs[w * 4 + i][f] = (r < n) ? X[(size_t)r * 64 + f] : 0.f;
    }
    __syncthreads();
    float acc[4] = {0.f, 0.f, 0.f, 0.f};
#pragma unroll 8
    for (int k = 0; k < 64; k++) {
        float wv = Ws[k * 64 + f];
#pragma unroll
        for (int i = 0; i < 4; i++) acc[i] += xs[w * 4 + i][k] * wv;
    }
#pragma unroll
    for (int i = 0; i < 4; i++) {
        int r = r0 + w * 4 + i;
        if (r < n) Y[(size_t)r * 64 + f] = dinv[r] * acc[i];
    }
}

// One wave per node, lane = feature. Unroll-8 clamped+predicated gathers
// (8 independent 256B row loads in flight). POOL: per-block partial mean.
template <bool POOL>
__global__ __launch_bounds__(256) void k_aggregate(const float* __restrict__ Y,
                                                   const float* __restrict__ dinv,
                                                   const float* __restrict__ bias,
                                                   const int* __restrict__ offsets,
                                                   const int* __restrict__ csr_src,
                                                   float* __restrict__ H,
                                                   float* __restrict__ pbuf, int n) {
    __shared__ float sm[256];
    int t = threadIdx.x, w = t >> 6, f = t & 63;
    int node = blockIdx.x * 4 + w;
    bool valid = node < n;
    float hval = 0.f;
    if (valid) {
        int beg = offsets[node], end = offsets[node + 1];
        float acc = Y[(size_t)node * 64 + f];  // self-loop term
        for (int j = beg; j < end; j += 8) {
#pragma unroll
            for (int u = 0; u < 8; u++) {
                int jj = j + u;
                bool c = jj < end;
                int jc = c ? jj : beg;  // safe: loop entered => beg < end
                int s = csr_src[jc];
                float a = Y[(size_t)s * 64 + f];
                acc += c ? a : 0.f;
            }
        }
        hval = fmaxf(dinv[node] * acc + bias[f], 0.f);
        if (!POOL) H[(size_t)node * 64 + f] = hval;
    }
    if (POOL) {
        sm[t] = valid ? hval : 0.f;
        __syncthreads();
        if (w == 0) pbuf[(size_t)blockIdx.x * 64 + f] =
            sm[f] + sm[64 + f] + sm[128 + f] + sm[192 + f];
    }
}

__global__ void k_mean_final(const float* __restrict__ pbuf, float* __restrict__ g,
                             int nrows) {
    __shared__ float part[256];
    int t = threadIdx.x, w = t >> 6, f = t & 63;
    float local = 0.f;
    for (int r = blockIdx.x * 4 + w; r < nrows; r += gridDim.x * 4)
        local += pbuf[(size_t)r * 64 + f];
    part[t] = local;
    __syncthreads();
    if (w == 0) {
        float tot = part[f] + part[64 + f] + part[128 + f] + part[192 + f];
        atomicAdd(&g[f], tot);
    }
}

__global__ void k_readout(const float* __restrict__ g, const float* __restrict__ Wr,
                          const float* __restrict__ br, float* __restrict__ out,
                          float invn) {
    __shared__ float gl[64];
    int t = threadIdx.x;
    if (t < 64) gl[t] = g[t] * invn;
    __syncthreads();
    float acc = br[t];
#pragma unroll
    for (int k = 0; k < 64; k++) acc += gl[k] * Wr[k * 128 + t];
    out[t] = acc;
}

extern "C" void kernel_launch(void* const* d_in, const int* in_sizes, int n_in,
                              void* d_out, int out_size, void* d_ws, size_t ws_size,
                              hipStream_t stream) {
    const float* x  = (const float*)d_in[0];
    const int*   ei = (const int*)d_in[1];   // int32 on device (JAX x64 off)
    const float* W1 = (const float*)d_in[2];
    const float* b1 = (const float*)d_in[3];
    const float* W2 = (const float*)d_in[4];
    const float* b2 = (const float*)d_in[5];
    const float* Wr = (const float*)d_in[6];
    const float* br = (const float*)d_in[7];
    float* out = (float*)d_out;

    int n = in_sizes[0] / 64;   // 50000
    int E = in_sizes[1] / 2;    // 800000
    const int* src = ei;
    const int* dst = ei + E;

    int NB  = (n + 63) / 64;        // 782 buckets of 64 nodes
    int nch = (E + CH - 1) / CH;    // 49 chunks

    // workspace layout (~32.5 MB)
    char* p = (char*)d_ws;
    float* y = (float*)p;      p += (size_t)n * 64 * sizeof(float);
    float* h = (float*)p;      p += (size_t)n * 64 * sizeof(float);
    float* dinv = (float*)p;   p += (size_t)n * sizeof(float);
    float* g = (float*)p;      p += 64 * sizeof(float);
    int* staged = (int*)p;     p += (size_t)E * sizeof(int);
    int* csr_src = (int*)p;    p += (size_t)E * sizeof(int);
    int* offsets = (int*)p;    p += (size_t)(n + 1) * sizeof(int);
    int* histmat = (int*)p;    p += (size_t)NB * nch * sizeof(int);
    int* bstart = (int*)p;     p += (size_t)(NB + 1) * sizeof(int);

    int gb = (n + 3) / 4;  // 12500 aggregate blocks (one wave per node)

    hipMemsetAsync(g, 0, 64 * sizeof(float), stream);
    k_bucket_hist<<<nch, 256, 0, stream>>>(dst, histmat, E, NB, nch);
    k_scan<<<1, 256, 0, stream>>>(histmat, bstart, offsets, NB, nch, E, n);
    k_bucket_scatter<<<nch, 256, 0, stream>>>(src, dst, histmat, staged, E, NB, nch);
    k_local_sort<<<NB, 256, 0, stream>>>(staged, bstart, csr_src, offsets, dinv, n);

    k_gemm_scale<<<(n + 15) / 16, 256, 0, stream>>>(x, W1, dinv, y, n);
    k_aggregate<false><<<gb, 256, 0, stream>>>(y, dinv, b1, offsets, csr_src, h, nullptr, n);
    k_gemm_scale<<<(n + 15) / 16, 256, 0, stream>>>(h, W2, dinv, y, n);
    float* pbuf = h;  // h dead after gemm2 -> reuse for per-bucket partials
    k_aggregate<true><<<gb, 256, 0, stream>>>(y, dinv, b2, offsets, csr_src, nullptr, pbuf, n);

    k_mean_final<<<64, 256, 0, stream>>>(pbuf, g, gb);
    k_readout<<<1, 128, 0, stream>>>(g, Wr, br, out, 1.0f / (float)n);
}

// Round 5
// 269.100 us; speedup vs baseline: 3.5423x; 1.1813x over previous
//
#include <hip/hip_runtime.h>
#include <math.h>

// SimpleGCN: h1 = relu(GCN(x,W1,b1)); h2 = relu(GCN(h1,W2,b2));
// g = mean(h2, axis=0); out = (g@Wr + br) -> 128 fp32.
// GCN(x,W,b)[d] = dinv[d]*( sum_{s in N(d)} y[s] + y[d] ) + b,
//   y = dinv * (x@W), dinv[i] = (1+indeg[i])^-0.5.
//
// R4 post-mortem: single-block k_scan was 69us (0.04% occupancy, per-thread
// serial stride-nch reads). R5: histmat transposed to chunk-major [nch][NB];
// per-bucket column scan is thread-parallel + coalesced (k_colscan), followed
// by a tiny 782-element scan (k_scanb). Build pipeline otherwise unchanged:
// bucket hist -> scatter (contiguous per-(chunk,bucket) runs, no global
// atomics) -> per-bucket LDS counting sort -> node-granular CSR feeding the
// wave-per-node unroll-8 aggregate.

#define CH 16384   // edges per chunk-block in hist/scatter
#define MAXNB 1024 // NB = ceil(n/64) <= 1024 (n <= 65536)

__global__ __launch_bounds__(256) void k_bucket_hist(const int* __restrict__ dst,
                                                     int* __restrict__ histmat,
                                                     int E, int NB) {
    __shared__ int ih[MAXNB];
    int t = threadIdx.x;
    for (int k = t; k < NB; k += 256) ih[k] = 0;
    __syncthreads();
    int base = blockIdx.x * CH;
    for (int i = 0; i < CH; i += 256) {
        int e = base + i + t;
        if (e < E) atomicAdd(&ih[dst[e] >> 6], 1);
    }
    __syncthreads();
    for (int k = t; k < NB; k += 256) histmat[(size_t)blockIdx.x * NB + k] = ih[k];
}

// thread per bucket: exclusive prefix over chunks (column of chunk-major
// histmat) in place + per-bucket total. Coalesced: consecutive threads hit
// consecutive addresses at every b.
__global__ __launch_bounds__(256) void k_colscan(int* __restrict__ histmat,
                                                 int* __restrict__ tot,
                                                 int NB, int nch) {
    int k = blockIdx.x * 256 + threadIdx.x;
    if (k >= NB) return;
    int run = 0;
    for (int b = 0; b < nch; b++) {
        int v = histmat[(size_t)b * NB + k];
        histmat[(size_t)b * NB + k] = run;
        run += v;
    }
    tot[k] = run;
}

// single block: exclusive scan of NB (<=1024) totals -> bstart; tails.
__global__ __launch_bounds__(256) void k_scanb(const int* __restrict__ tot,
                                               int* __restrict__ bstart,
                                               int* __restrict__ offsets,
                                               int NB, int E, int n) {
    __shared__ int sc[256];
    __shared__ int carry;
    int t = threadIdx.x;
    if (t == 0) carry = 0;
    __syncthreads();
    int nchunk = (NB + 255) / 256;
    for (int c = 0; c < nchunk; c++) {
        int idx = c * 256 + t;
        int v = (idx < NB) ? tot[idx] : 0;
        sc[t] = v;
        __syncthreads();
        for (int off = 1; off < 256; off <<= 1) {
            int x = (t >= off) ? sc[t - off] : 0;
            __syncthreads();
            sc[t] += x;
            __syncthreads();
        }
        if (idx < NB) bstart[idx] = sc[t] - v + carry;
        __syncthreads();
        if (t == 0) carry += sc[255];
        __syncthreads();
    }
    if (t == 0) { bstart[NB] = E; offsets[n] = E; }
}

__global__ __launch_bounds__(256) void k_bucket_scatter(const int* __restrict__ src,
                                                        const int* __restrict__ dst,
                                                        const int* __restrict__ histmat,
                                                        const int* __restrict__ bstart,
                                                        int* __restrict__ staged,
                                                        int E, int NB) {
    __shared__ int cur[MAXNB];
    int t = threadIdx.x;
    for (int k = t; k < NB; k += 256)
        cur[k] = bstart[k] + histmat[(size_t)blockIdx.x * NB + k];
    __syncthreads();
    int base = blockIdx.x * CH;
    for (int i = 0; i < CH; i += 256) {
        int e = base + i + t;
        if (e < E) {
            int d = dst[e];
            int pos = atomicAdd(&cur[d >> 6], 1);
            staged[pos] = (src[e] << 6) | (d & 63);  // n<=65536 -> fits
        }
    }
}

// one block per bucket: counting-sort the bucket's staged run into node-
// granular CSR (writes stay in the bucket's contiguous window); emit
// per-node offsets + dinv from the counts. ~1k edges/bucket.
__global__ __launch_bounds__(256) void k_local_sort(const int* __restrict__ staged,
                                                    const int* __restrict__ bstart,
                                                    int* __restrict__ csr_src,
                                                    int* __restrict__ offsets,
                                                    float* __restrict__ dinv, int n) {
    __shared__ int cnt[64];
    __shared__ int pos[64];
    __shared__ int cur[64];
    int t = threadIdx.x;
    if (t < 64) cnt[t] = 0;
    __syncthreads();
    int k = blockIdx.x;
    int beg = bstart[k], end = bstart[k + 1];
    for (int e = beg + t; e < end; e += 256) atomicAdd(&cnt[staged[e] & 63], 1);
    __syncthreads();
    if (t == 0) {
        int run = 0;
        for (int i = 0; i < 64; i++) { pos[i] = run; run += cnt[i]; }
    }
    __syncthreads();
    if (t < 64) {
        cur[t] = pos[t];
        int node = k * 64 + t;
        if (node < n) {
            offsets[node] = beg + pos[t];
            dinv[node] = 1.0f / sqrtf((float)(cnt[t] + 1));  // + self-loop
        }
    }
    __syncthreads();
    for (int e = beg + t; e < end; e += 256) {
        int pk = staged[e];
        int p = atomicAdd(&cur[pk & 63], 1);
        csr_src[beg + p] = pk >> 6;
    }
}

// Y[i,:] = dinv[i] * (X[i,:] @ W). 16 rows/block, 4 rows/wave: one LDS read
// of W[k][f] feeds 4 FMAs.
__global__ __launch_bounds__(256) void k_gemm_scale(const float* __restrict__ X,
                                                    const float* __restrict__ W,
                                                    const float* __restrict__ dinv,
                                                    float* __restrict__ Y, int n) {
    __shared__ float Ws[64 * 64];
    __shared__ float xs[16][64];
    int t = threadIdx.x, w = t >> 6, f = t & 63;
    const float4* W4 = (const float4*)W;
    float4* Ws4 = (float4*)Ws;
#pragma unroll
    for (int j = 0; j < 4; j++) Ws4[t + 256 * j] = W4[t + 256 * j];
    int r0 = blockIdx.x * 16;
#pragma unroll
    for (int i = 0; i < 4; i++) {
        int r = r0 + w * 4 + i;
        xs[w * 4 + i][f] = (r < n) ? X[(size_t)r * 64 + f] : 0.f;
    }
    __syncthreads();
    float acc[4] = {0.f, 0.f, 0.f, 0.f};
#pragma unroll 8
    for (int k = 0; k < 64; k++) {
        float wv = Ws[k * 64 + f];
#pragma unroll
        for (int i = 0; i < 4; i++) acc[i] += xs[w * 4 + i][k] * wv;
    }
#pragma unroll
    for (int i = 0; i < 4; i++) {
        int r = r0 + w * 4 + i;
        if (r < n) Y[(size_t)r * 64 + f] = dinv[r] * acc[i];
    }
}

// One wave per node, lane = feature. Unroll-8 clamped+predicated gathers
// (8 independent 256B row loads in flight). POOL: per-block partial mean.
template <bool POOL>
__global__ __launch_bounds__(256) void k_aggregate(const float* __restrict__ Y,
                                                   const float* __restrict__ dinv,
                                                   const float* __restrict__ bias,
                                                   const int* __restrict__ offsets,
                                                   const int* __restrict__ csr_src,
                                                   float* __restrict__ H,
                                                   float* __restrict__ pbuf, int n) {
    __shared__ float sm[256];
    int t = threadIdx.x, w = t >> 6, f = t & 63;
    int node = blockIdx.x * 4 + w;
    bool valid = node < n;
    float hval = 0.f;
    if (valid) {
        int beg = offsets[node], end = offsets[node + 1];
        float acc = Y[(size_t)node * 64 + f];  // self-loop term
        for (int j = beg; j < end; j += 8) {
#pragma unroll
            for (int u = 0; u < 8; u++) {
                int jj = j + u;
                bool c = jj < end;
                int jc = c ? jj : beg;  // safe: loop entered => beg < end
                int s = csr_src[jc];
                float a = Y[(size_t)s * 64 + f];
                acc += c ? a : 0.f;
            }
        }
        hval = fmaxf(dinv[node] * acc + bias[f], 0.f);
        if (!POOL) H[(size_t)node * 64 + f] = hval;
    }
    if (POOL) {
        sm[t] = valid ? hval : 0.f;
        __syncthreads();
        if (w == 0) pbuf[(size_t)blockIdx.x * 64 + f] =
            sm[f] + sm[64 + f] + sm[128 + f] + sm[192 + f];
    }
}

__global__ void k_mean_final(const float* __restrict__ pbuf, float* __restrict__ g,
                             int nrows) {
    __shared__ float part[256];
    int t = threadIdx.x, w = t >> 6, f = t & 63;
    float local = 0.f;
    for (int r = blockIdx.x * 4 + w; r < nrows; r += gridDim.x * 4)
        local += pbuf[(size_t)r * 64 + f];
    part[t] = local;
    __syncthreads();
    if (w == 0) {
        float tot = part[f] + part[64 + f] + part[128 + f] + part[192 + f];
        atomicAdd(&g[f], tot);
    }
}

__global__ void k_readout(const float* __restrict__ g, const float* __restrict__ Wr,
                          const float* __restrict__ br, float* __restrict__ out,
                          float invn) {
    __shared__ float gl[64];
    int t = threadIdx.x;
    if (t < 64) gl[t] = g[t] * invn;
    __syncthreads();
    float acc = br[t];
#pragma unroll
    for (int k = 0; k < 64; k++) acc += gl[k] * Wr[k * 128 + t];
    out[t] = acc;
}

extern "C" void kernel_launch(void* const* d_in, const int* in_sizes, int n_in,
                              void* d_out, int out_size, void* d_ws, size_t ws_size,
                              hipStream_t stream) {
    const float* x  = (const float*)d_in[0];
    const int*   ei = (const int*)d_in[1];   // int32 on device (JAX x64 off)
    const float* W1 = (const float*)d_in[2];
    const float* b1 = (const float*)d_in[3];
    const float* W2 = (const float*)d_in[4];
    const float* b2 = (const float*)d_in[5];
    const float* Wr = (const float*)d_in[6];
    const float* br = (const float*)d_in[7];
    float* out = (float*)d_out;

    int n = in_sizes[0] / 64;   // 50000
    int E = in_sizes[1] / 2;    // 800000
    const int* src = ei;
    const int* dst = ei + E;

    int NB  = (n + 63) / 64;        // 782 buckets of 64 nodes
    int nch = (E + CH - 1) / CH;    // 49 chunks

    // workspace layout (~32.5 MB)
    char* p = (char*)d_ws;
    float* y = (float*)p;      p += (size_t)n * 64 * sizeof(float);
    float* h = (float*)p;      p += (size_t)n * 64 * sizeof(float);
    float* dinv = (float*)p;   p += (size_t)n * sizeof(float);
    float* g = (float*)p;      p += 64 * sizeof(float);
    int* staged = (int*)p;     p += (size_t)E * sizeof(int);
    int* csr_src = (int*)p;    p += (size_t)E * sizeof(int);
    int* offsets = (int*)p;    p += (size_t)(n + 1) * sizeof(int);
    int* histmat = (int*)p;    p += (size_t)nch * NB * sizeof(int);  // chunk-major
    int* tot = (int*)p;        p += (size_t)NB * sizeof(int);
    int* bstart = (int*)p;     p += (size_t)(NB + 1) * sizeof(int);

    int gb = (n + 3) / 4;  // 12500 aggregate blocks (one wave per node)

    hipMemsetAsync(g, 0, 64 * sizeof(float), stream);
    k_bucket_hist<<<nch, 256, 0, stream>>>(dst, histmat, E, NB);
    k_colscan<<<(NB + 255) / 256, 256, 0, stream>>>(histmat, tot, NB, nch);
    k_scanb<<<1, 256, 0, stream>>>(tot, bstart, offsets, NB, E, n);
    k_bucket_scatter<<<nch, 256, 0, stream>>>(src, dst, histmat, bstart, staged, E, NB);
    k_local_sort<<<NB, 256, 0, stream>>>(staged, bstart, csr_src, offsets, dinv, n);

    k_gemm_scale<<<(n + 15) / 16, 256, 0, stream>>>(x, W1, dinv, y, n);
    k_aggregate<false><<<gb, 256, 0, stream>>>(y, dinv, b1, offsets, csr_src, h, nullptr, n);
    k_gemm_scale<<<(n + 15) / 16, 256, 0, stream>>>(h, W2, dinv, y, n);
    float* pbuf = h;  // h dead after gemm2 -> reuse for per-bucket partials
    k_aggregate<true><<<gb, 256, 0, stream>>>(y, dinv, b2, offsets, csr_src, nullptr, pbuf, n);

    k_mean_final<<<64, 256, 0, stream>>>(pbuf, g, gb);
    k_readout<<<1, 128, 0, stream>>>(g, Wr, br, out, 1.0f / (float)n);
}

// Round 6
// 231.602 us; speedup vs baseline: 4.1158x; 1.1619x over previous
//
#include <hip/hip_runtime.h>
#include <math.h>

// SimpleGCN: h1 = relu(GCN(x,W1,b1)); h2 = relu(GCN(h1,W2,b2));
// g = mean(h2, axis=0); out = (g@Wr + br) -> 128 fp32.
// GCN(x,W,b)[d] = dinv[d]*( sum_{s in N(d)} y[s] + y[d] ) + b,
//   y = dinv * (x@W), dinv[i] = (1+indeg[i])^-0.5.
//
// R5 post-mortem: k_bucket_scatter 50us at 1.8% occupancy (49 blocks).
// R6: (a) CH 16384->4096 => 196 hist/scatter blocks (colscan load phase
// manually unrolled x8 to keep 8 loads in flight over the longer chunk dim);
// (b) aggregate reworked to float4 lanes: lane=(edge_slot q, feat4 c), one
// dwordx4 row-load per 16 lanes => 4 edges per wave-load, 4x bytes in
// flight; cross-slot reduce via 2 shfl_xor butterflies.

#define CH 4096    // edges per chunk-block in hist/scatter
#define MAXNB 1024 // NB = ceil(n/64) <= 1024 (n <= 65536)

__global__ __launch_bounds__(256) void k_bucket_hist(const int* __restrict__ dst,
                                                     int* __restrict__ histmat,
                                                     int E, int NB) {
    __shared__ int ih[MAXNB];
    int t = threadIdx.x;
    for (int k = t; k < NB; k += 256) ih[k] = 0;
    __syncthreads();
    int base = blockIdx.x * CH;
    for (int i = 0; i < CH; i += 256) {
        int e = base + i + t;
        if (e < E) atomicAdd(&ih[dst[e] >> 6], 1);
    }
    __syncthreads();
    for (int k = t; k < NB; k += 256) histmat[(size_t)blockIdx.x * NB + k] = ih[k];
}

// thread per bucket: exclusive prefix over chunks (column of chunk-major
// histmat) in place + per-bucket total. Coalesced across threads; unroll-8
// keeps 8 loads in flight along the serial chunk dimension.
__global__ __launch_bounds__(256) void k_colscan(int* __restrict__ histmat,
                                                 int* __restrict__ tot,
                                                 int NB, int nch) {
    int k = blockIdx.x * 256 + threadIdx.x;
    if (k >= NB) return;
    int run = 0;
    int b = 0;
    for (; b + 8 <= nch; b += 8) {
        int v[8];
#pragma unroll
        for (int u = 0; u < 8; u++) v[u] = histmat[(size_t)(b + u) * NB + k];
#pragma unroll
        for (int u = 0; u < 8; u++) {
            int x = v[u];
            histmat[(size_t)(b + u) * NB + k] = run;
            run += x;
        }
    }
    for (; b < nch; b++) {
        int x = histmat[(size_t)b * NB + k];
        histmat[(size_t)b * NB + k] = run;
        run += x;
    }
    tot[k] = run;
}

// single block: exclusive scan of NB (<=1024) totals -> bstart; tails.
__global__ __launch_bounds__(256) void k_scanb(const int* __restrict__ tot,
                                               int* __restrict__ bstart,
                                               int* __restrict__ offsets,
                                               int NB, int E, int n) {
    __shared__ int sc[256];
    __shared__ int carry;
    int t = threadIdx.x;
    if (t == 0) carry = 0;
    __syncthreads();
    int nchunk = (NB + 255) / 256;
    for (int c = 0; c < nchunk; c++) {
        int idx = c * 256 + t;
        int v = (idx < NB) ? tot[idx] : 0;
        sc[t] = v;
        __syncthreads();
        for (int off = 1; off < 256; off <<= 1) {
            int x = (t >= off) ? sc[t - off] : 0;
            __syncthreads();
            sc[t] += x;
            __syncthreads();
        }
        if (idx < NB) bstart[idx] = sc[t] - v + carry;
        __syncthreads();
        if (t == 0) carry += sc[255];
        __syncthreads();
    }
    if (t == 0) { bstart[NB] = E; offsets[n] = E; }
}

__global__ __launch_bounds__(256) void k_bucket_scatter(const int* __restrict__ src,
                                                        const int* __restrict__ dst,
                                                        const int* __restrict__ histmat,
                                                        const int* __restrict__ bstart,
                                                        int* __restrict__ staged,
                                                        int E, int NB) {
    __shared__ int cur[MAXNB];
    int t = threadIdx.x;
    for (int k = t; k < NB; k += 256)
        cur[k] = bstart[k] + histmat[(size_t)blockIdx.x * NB + k];
    __syncthreads();
    int base = blockIdx.x * CH;
    for (int i = 0; i < CH; i += 256) {
        int e = base + i + t;
        if (e < E) {
            int d = dst[e];
            int pos = atomicAdd(&cur[d >> 6], 1);
            staged[pos] = (src[e] << 6) | (d & 63);  // n<=65536 -> fits
        }
    }
}

// one block per bucket: counting-sort the bucket's staged run into node-
// granular CSR (writes stay in the bucket's contiguous window); emit
// per-node offsets + dinv from the counts. ~1k edges/bucket.
__global__ __launch_bounds__(256) void k_local_sort(const int* __restrict__ staged,
                                                    const int* __restrict__ bstart,
                                                    int* __restrict__ csr_src,
                                                    int* __restrict__ offsets,
                                                    float* __restrict__ dinv, int n) {
    __shared__ int cnt[64];
    __shared__ int pos[64];
    __shared__ int cur[64];
    int t = threadIdx.x;
    if (t < 64) cnt[t] = 0;
    __syncthreads();
    int k = blockIdx.x;
    int beg = bstart[k], end = bstart[k + 1];
    for (int e = beg + t; e < end; e += 256) atomicAdd(&cnt[staged[e] & 63], 1);
    __syncthreads();
    if (t == 0) {
        int run = 0;
        for (int i = 0; i < 64; i++) { pos[i] = run; run += cnt[i]; }
    }
    __syncthreads();
    if (t < 64) {
        cur[t] = pos[t];
        int node = k * 64 + t;
        if (node < n) {
            offsets[node] = beg + pos[t];
            dinv[node] = 1.0f / sqrtf((float)(cnt[t] + 1));  // + self-loop
        }
    }
    __syncthreads();
    for (int e = beg + t; e < end; e += 256) {
        int pk = staged[e];
        int p = atomicAdd(&cur[pk & 63], 1);
        csr_src[beg + p] = pk >> 6;
    }
}

// Y[i,:] = dinv[i] * (X[i,:] @ W). 16 rows/block, 4 rows/wave: one LDS read
// of W[k][f] feeds 4 FMAs.
__global__ __launch_bounds__(256) void k_gemm_scale(const float* __restrict__ X,
                                                    const float* __restrict__ W,
                                                    const float* __restrict__ dinv,
                                                    float* __restrict__ Y, int n) {
    __shared__ float Ws[64 * 64];
    __shared__ float xs[16][64];
    int t = threadIdx.x, w = t >> 6, f = t & 63;
    const float4* W4 = (const float4*)W;
    float4* Ws4 = (float4*)Ws;
#pragma unroll
    for (int j = 0; j < 4; j++) Ws4[t + 256 * j] = W4[t + 256 * j];
    int r0 = blockIdx.x * 16;
#pragma unroll
    for (int i = 0; i < 4; i++) {
        int r = r0 + w * 4 + i;
        xs[w * 4 + i][f] = (r < n) ? X[(size_t)r * 64 + f] : 0.f;
    }
    __syncthreads();
    float acc[4] = {0.f, 0.f, 0.f, 0.f};
#pragma unroll 8
    for (int k = 0; k < 64; k++) {
        float wv = Ws[k * 64 + f];
#pragma unroll
        for (int i = 0; i < 4; i++) acc[i] += xs[w * 4 + i][k] * wv;
    }
#pragma unroll
    for (int i = 0; i < 4; i++) {
        int r = r0 + w * 4 + i;
        if (r < n) Y[(size_t)r * 64 + f] = dinv[r] * acc[i];
    }
}

// One wave per node. lane = (q,c): q=lane>>4 edge slot, c=lane&15 float4
// column. Each slot loads a full 64-float row with 16 dwordx4 lanes ->
// 4 edges per wave-load, unroll-4 => 16 KB in flight per wave. Cross-slot
// reduce: shfl_xor(16), shfl_xor(32). POOL: per-block partial mean rows.
template <bool POOL>
__global__ __launch_bounds__(256) void k_aggregate(const float* __restrict__ Y,
                                                   const float* __restrict__ dinv,
                                                   const float* __restrict__ bias,
                                                   const int* __restrict__ offsets,
                                                   const int* __restrict__ csr_src,
                                                   float* __restrict__ H,
                                                   float* __restrict__ pbuf, int n) {
    __shared__ float4 sm4[4][16];
    const float4* Y4 = (const float4*)Y;
    int t = threadIdx.x, w = t >> 6, l = t & 63;
    int q = l >> 4, c = l & 15;
    int node = blockIdx.x * 4 + w;
    bool valid = node < n;
    float4 hval = make_float4(0.f, 0.f, 0.f, 0.f);
    if (valid) {
        float4 acc = make_float4(0.f, 0.f, 0.f, 0.f);
        if (q == 0) acc = Y4[(size_t)node * 16 + c];  // self-loop term
        int beg = offsets[node], end = offsets[node + 1];
        for (int j = beg + q; j < end; j += 16) {
#pragma unroll
            for (int u = 0; u < 4; u++) {
                int jj = j + 4 * u;
                bool ok = jj < end;
                float4 v = make_float4(0.f, 0.f, 0.f, 0.f);
                if (ok) {
                    int s = csr_src[jj];           // uniform within slot
                    v = Y4[(size_t)s * 16 + c];    // 16 lanes x 16B = row
                }
                acc.x += v.x; acc.y += v.y; acc.z += v.z; acc.w += v.w;
            }
        }
        // reduce across the 4 edge slots (lane bits 4,5)
#pragma unroll
        for (int m = 16; m <= 32; m <<= 1) {
            acc.x += __shfl_xor(acc.x, m);
            acc.y += __shfl_xor(acc.y, m);
            acc.z += __shfl_xor(acc.z, m);
            acc.w += __shfl_xor(acc.w, m);
        }
        float dv = dinv[node];
        float4 b4 = ((const float4*)bias)[c];
        hval.x = fmaxf(dv * acc.x + b4.x, 0.f);
        hval.y = fmaxf(dv * acc.y + b4.y, 0.f);
        hval.z = fmaxf(dv * acc.z + b4.z, 0.f);
        hval.w = fmaxf(dv * acc.w + b4.w, 0.f);
        if (!POOL && q == 0) ((float4*)H)[(size_t)node * 16 + c] = hval;
    }
    if (POOL) {
        if (q == 0) sm4[w][c] = valid ? hval : make_float4(0.f, 0.f, 0.f, 0.f);
        __syncthreads();
        if (t < 16) {
            float4 a = sm4[0][t], b = sm4[1][t], d = sm4[2][t], e = sm4[3][t];
            float4 s;
            s.x = (a.x + b.x) + (d.x + e.x);
            s.y = (a.y + b.y) + (d.y + e.y);
            s.z = (a.z + b.z) + (d.z + e.z);
            s.w = (a.w + b.w) + (d.w + e.w);
            ((float4*)pbuf)[(size_t)blockIdx.x * 16 + t] = s;
        }
    }
}

__global__ void k_mean_final(const float* __restrict__ pbuf, float* __restrict__ g,
                             int nrows) {
    __shared__ float part[256];
    int t = threadIdx.x, w = t >> 6, f = t & 63;
    float local = 0.f;
    for (int r = blockIdx.x * 4 + w; r < nrows; r += gridDim.x * 4)
        local += pbuf[(size_t)r * 64 + f];
    part[t] = local;
    __syncthreads();
    if (w == 0) {
        float tot = part[f] + part[64 + f] + part[128 + f] + part[192 + f];
        atomicAdd(&g[f], tot);
    }
}

__global__ void k_readout(const float* __restrict__ g, const float* __restrict__ Wr,
                          const float* __restrict__ br, float* __restrict__ out,
                          float invn) {
    __shared__ float gl[64];
    int t = threadIdx.x;
    if (t < 64) gl[t] = g[t] * invn;
    __syncthreads();
    float acc = br[t];
#pragma unroll
    for (int k = 0; k < 64; k++) acc += gl[k] * Wr[k * 128 + t];
    out[t] = acc;
}

extern "C" void kernel_launch(void* const* d_in, const int* in_sizes, int n_in,
                              void* d_out, int out_size, void* d_ws, size_t ws_size,
                              hipStream_t stream) {
    const float* x  = (const float*)d_in[0];
    const int*   ei = (const int*)d_in[1];   // int32 on device (JAX x64 off)
    const float* W1 = (const float*)d_in[2];
    const float* b1 = (const float*)d_in[3];
    const float* W2 = (const float*)d_in[4];
    const float* b2 = (const float*)d_in[5];
    const float* Wr = (const float*)d_in[6];
    const float* br = (const float*)d_in[7];
    float* out = (float*)d_out;

    int n = in_sizes[0] / 64;   // 50000
    int E = in_sizes[1] / 2;    // 800000
    const int* src = ei;
    const int* dst = ei + E;

    int NB  = (n + 63) / 64;        // 782 buckets of 64 nodes
    int nch = (E + CH - 1) / CH;    // 196 chunks

    // workspace layout (~33 MB)
    char* p = (char*)d_ws;
    float* y = (float*)p;      p += (size_t)n * 64 * sizeof(float);
    float* h = (float*)p;      p += (size_t)n * 64 * sizeof(float);
    float* dinv = (float*)p;   p += (size_t)n * sizeof(float);
    float* g = (float*)p;      p += 64 * sizeof(float);
    int* staged = (int*)p;     p += (size_t)E * sizeof(int);
    int* csr_src = (int*)p;    p += (size_t)E * sizeof(int);
    int* offsets = (int*)p;    p += (size_t)(n + 1) * sizeof(int);
    int* histmat = (int*)p;    p += (size_t)nch * NB * sizeof(int);  // chunk-major
    int* tot = (int*)p;        p += (size_t)NB * sizeof(int);
    int* bstart = (int*)p;     p += (size_t)(NB + 1) * sizeof(int);

    int gb = (n + 3) / 4;  // 12500 aggregate blocks (one wave per node)

    hipMemsetAsync(g, 0, 64 * sizeof(float), stream);
    k_bucket_hist<<<nch, 256, 0, stream>>>(dst, histmat, E, NB);
    k_colscan<<<(NB + 255) / 256, 256, 0, stream>>>(histmat, tot, NB, nch);
    k_scanb<<<1, 256, 0, stream>>>(tot, bstart, offsets, NB, E, n);
    k_bucket_scatter<<<nch, 256, 0, stream>>>(src, dst, histmat, bstart, staged, E, NB);
    k_local_sort<<<NB, 256, 0, stream>>>(staged, bstart, csr_src, offsets, dinv, n);

    k_gemm_scale<<<(n + 15) / 16, 256, 0, stream>>>(x, W1, dinv, y, n);
    k_aggregate<false><<<gb, 256, 0, stream>>>(y, dinv, b1, offsets, csr_src, h, nullptr, n);
    k_gemm_scale<<<(n + 15) / 16, 256, 0, stream>>>(h, W2, dinv, y, n);
    float* pbuf = h;  // h dead after gemm2 -> reuse for per-block partials
    k_aggregate<true><<<gb, 256, 0, stream>>>(y, dinv, b2, offsets, csr_src, nullptr, pbuf, n);

    k_mean_final<<<64, 256, 0, stream>>>(pbuf, g, gb);
    k_readout<<<1, 128, 0, stream>>>(g, Wr, br, out, 1.0f / (float)n);
}